// Round 7
// baseline (533.631 us; speedup 1.0000x reference)
//
#include <hip/hip_runtime.h>
#include <cstdint>
#include <cstddef>

#define KIN 300
#define KPAD 320
#define HIDDEN 128
#define BSZ 256
#define TSZ 512

// Phase-1 LDS row stride (shorts). 332*2/4 = 166 ≡ 6 (mod 32): bank spread.
#define ASTR 332

typedef __attribute__((ext_vector_type(8))) short short8;
typedef __attribute__((ext_vector_type(4))) short s16x4;
typedef __attribute__((ext_vector_type(4))) float f32x4;

__device__ __forceinline__ short f2bf(float f) {
  uint32_t u = __builtin_bit_cast(uint32_t, f);
  u = (u + 0x7FFFu + ((u >> 16) & 1u)) >> 16;
  return (short)u;
}
__device__ __forceinline__ float bf2f(short s) {
  uint32_t u = ((uint32_t)(uint16_t)s) << 16;
  return __builtin_bit_cast(float, u);
}
__device__ __forceinline__ float bflo(uint32_t u) {
  return __builtin_bit_cast(float, u << 16);
}
__device__ __forceinline__ float bfhi(uint32_t u) {
  return __builtin_bit_cast(float, u & 0xFFFF0000u);
}
// HW packed f32->bf16 RNE convert: lo = bf16(a), hi = bf16(b). 1 inst vs ~10.
__device__ __forceinline__ uint32_t pack2bf(float a, float b) {
  uint32_t r;
  asm("v_cvt_pk_bf16_f32 %0, %1, %2" : "=v"(r) : "v"(a), "v"(b));
  return r;
}
// tanh(x) = 1 - 2/(exp2(x*2*log2e)+1); exact at +/-1 extremes, 5 VALU inst.
__device__ __forceinline__ float tanhf_fast(float v) {
  const float e = __builtin_amdgcn_exp2f(v * 2.88539008177793f);
  return fmaf(-2.0f, __builtin_amdgcn_rcpf(e + 1.0f), 1.0f);
}
// Barrier that waits LDS ops but leaves global/DMA (vmcnt) in flight.
__device__ __forceinline__ void barrier_lds() {
  asm volatile("s_waitcnt lgkmcnt(0)\n\ts_barrier" ::: "memory");
}
// async 16B/lane global->LDS DMA: lds dst = uniform base + lane*16
__device__ __forceinline__ void dma16(const short* g, short* l) {
  __builtin_amdgcn_global_load_lds(
      (const __attribute__((address_space(1))) void*)g,
      (__attribute__((address_space(3))) void*)l, 16, 0, 0);
}
// Load a bf16 MFMA fragment from the split ht layout: 8 values as two
// separated short4 groups (can't be merged into a conflicting b128).
__device__ __forceinline__ short8 ld_bh(const short* lo) {
  const s16x4 a = *(const s16x4*)lo;
  const s16x4 b = *(const s16x4*)(lo + 64);
  return __builtin_shufflevector(a, b, 0, 1, 2, 3, 4, 5, 6, 7);
}
// W_ih A-frag converted from float in-register (replaces wcvt/W16): row-major
// float W, 8 elems at k0, zero-padded past KIN. Fast float4 path when whole
// frag is in-bounds (aligned: row*300*4 % 16 == 0, k0 % 8 == 0).
__device__ __forceinline__ short8 ldWfrag(const float* __restrict__ W, int row,
                                          int k0) {
  short8 t;
  const float* p = W + (size_t)row * KIN + k0;
  if (k0 + 8 <= KIN) {
    const float4 v0 = *(const float4*)(p);
    const float4 v1 = *(const float4*)(p + 4);
    t[0] = f2bf(v0.x); t[1] = f2bf(v0.y); t[2] = f2bf(v0.z); t[3] = f2bf(v0.w);
    t[4] = f2bf(v1.x); t[5] = f2bf(v1.y); t[6] = f2bf(v1.z); t[7] = f2bf(v1.w);
  } else {
#pragma unroll
    for (int j = 0; j < 8; ++j) {
      const int k = k0 + j;
      t[j] = (k < KIN) ? f2bf(p[j]) : (short)0;
    }
  }
  return t;
}

// LDS: one union so producer (As) and consumer (xs+ht) shapes share the
// allocation; 104.25 KB -> 1 block/CU everywhere, no producer/consumer
// co-residency on the 16 scan CUs.
union SMemU {
  short As[64 * ASTR];  // producer: 42.5 KB stage + epilogue
  struct {
    short xs[3][8][2048];  // consumer: 96 KB, 3-deep chunk buffers
    short ht[2][16][132];  // consumer: 8.25 KB split-col h state
  } c;
};

// ---------------- Fused kernel: blocks 0-15 scan, 16-2063 produce ----------
__global__ __launch_bounds__(512, 1) void rnn_fused(
    const float* __restrict__ x, const float* __restrict__ Wih,
    const float* __restrict__ Whh, const float* __restrict__ b_ih,
    const float* __restrict__ b_hh, const float* __restrict__ fc_w,
    const float* __restrict__ fc_b, short* __restrict__ xp16,
    int* __restrict__ flags, float* __restrict__ out) {
  __shared__ __align__(16) union SMemU sm;
  const int tid = threadIdx.x;
  const int lane = tid & 63, w = tid >> 6;  // w = 0..7
  const int q = lane >> 4, c = lane & 15;

  if (blockIdx.x >= 16) {
    // =================== PRODUCER: xp tile (16 b x 4 t) ====================
    const int pid = blockIdx.x - 16;
    const int bg = pid & 15, tc = pid >> 4;  // tc 0..127
    const int b0 = bg * 16, t0 = tc * 4;
    short* As = sm.As;

    // ---- stage x tile (64 rows x 300 K) as bf16, padded stride ASTR ----
#pragma unroll
    for (int i = 0; i < 10; ++i) {
      const int f = tid + 512 * i;  // float4 index over 64*75
      if (f < 4800) {
        const int rr = f / 75;
        const int k4 = f - rr * 75;
        const int b_in = rr >> 2, t_loc = rr & 3;
        const float4 v = *(const float4*)(
            x + ((size_t)(b0 + b_in) * TSZ + t0 + t_loc) * KIN + k4 * 4);
        uint2 pv;
        pv.x = pack2bf(v.x, v.y);
        pv.y = pack2bf(v.z, v.w);
        *(uint2*)&As[rr * ASTR + k4 * 4] = pv;
      }
    }
    if (tid < 64) {  // zero-pad k = 300..319
      const uint2 z = {0u, 0u};
#pragma unroll
      for (int j = 0; j < 5; ++j) *(uint2*)&As[tid * ASTR + 300 + j * 4] = z;
    }
    __syncthreads();

    // wave w owns h rows [16w, 16w+16) x all 4 row-tiles
    f32x4 acc[4];
#pragma unroll
    for (int rt = 0; rt < 4; ++rt) acc[rt] = (f32x4){0.f, 0.f, 0.f, 0.f};
    const int row = w * 16 + c;
    const short* bqp = &As[c * ASTR + q * 8];
    short8 af[2];
    short8 bq[2][4];
    af[0] = ldWfrag(Wih, row, q * 8);
#pragma unroll
    for (int rt = 0; rt < 4; ++rt)
      bq[0][rt] = *(const short8*)(bqp + rt * 16 * ASTR);
#pragma unroll
    for (int kc = 0; kc < 10; ++kc) {
      const int cur = kc & 1;
      if (kc < 9) {
        af[cur ^ 1] = ldWfrag(Wih, row, (kc + 1) * 32 + q * 8);
#pragma unroll
        for (int rt = 0; rt < 4; ++rt)
          bq[cur ^ 1][rt] =
              *(const short8*)(bqp + rt * 16 * ASTR + (kc + 1) * 32);
      }
#pragma unroll
      for (int rt = 0; rt < 4; ++rt)
        acc[rt] = __builtin_amdgcn_mfma_f32_16x16x32_bf16(af[cur], bq[cur][rt],
                                                          acc[rt], 0, 0, 0);
    }
    __syncthreads();  // B-frag reads done; As becomes the stage buffer

    // ---- epilogue: bias, pack, LDS transpose to [t][g][b][4] ----
    const int h0 = w * 16 + q * 4;
    const float4 bi = *(const float4*)(b_ih + h0);
    const float4 bh = *(const float4*)(b_hh + h0);
    const float4 bsum =
        make_float4(bi.x + bh.x, bi.y + bh.y, bi.z + bh.z, bi.w + bh.w);
    const int g = w * 4 + q;  // h-group h/4, each (w,q) unique in [0,32)
#pragma unroll
    for (int rt = 0; rt < 4; ++rt) {
      const int b_in = rt * 4 + (c >> 2);
      const int t_loc = c & 3;
      uint2 pv;
      pv.x = pack2bf(acc[rt][0] + bsum.x, acc[rt][1] + bsum.y);
      pv.y = pack2bf(acc[rt][2] + bsum.z, acc[rt][3] + bsum.w);
      *(uint2*)&As[t_loc * 2312 + g * 72 + b_in * 4] = pv;
    }
    __syncthreads();
    // ---- coalesced copy-out: per t_loc a dense 4 KB region ----
#pragma unroll
    for (int i = 0; i < 2; ++i) {
      const int t_loc = i * 2 + (tid >> 8);
      const int inner = tid & 255;
      const int4 vv =
          *(const int4*)&As[t_loc * 2312 + (inner >> 3) * 72 + (inner & 7) * 8];
      *(int4*)(xp16 + ((size_t)(t0 + t_loc) * 16 + bg) * 2048 + inner * 8) = vv;
    }
    __syncthreads();  // drains vmcnt: all 512 threads' stores are in L2
    if (tid == 0) {
      // agent release: writeback this XCD's L2 so the flag implies the data
      __builtin_amdgcn_fence(__ATOMIC_RELEASE, "agent");
      __hip_atomic_fetch_add(&flags[bg * 64 + (tc >> 1)], 1, __ATOMIC_RELAXED,
                             __HIP_MEMORY_SCOPE_AGENT);
    }
    return;
  }

  // ===================== CONSUMER: r2 scan + flag gates ====================
  const int bg = blockIdx.x;
  short(*xs)[8][2048] = sm.c.xs;
  short(*ht)[16][132] = sm.c.ht;

  // W_hh A-frags: wave w owns h-out rows [16w, 16w+16); one frag per K-chunk.
  short8 aw[4];
#pragma unroll
  for (int kc = 0; kc < 4; ++kc) {
    const float* src = Whh + (size_t)(w * 16 + c) * HIDDEN + kc * 32 + q * 8;
    const float4 v0 = *(const float4*)(src);
    const float4 v1 = *(const float4*)(src + 4);
    short8 t;
    t[0] = f2bf(v0.x); t[1] = f2bf(v0.y); t[2] = f2bf(v0.z); t[3] = f2bf(v0.w);
    t[4] = f2bf(v1.x); t[5] = f2bf(v1.y); t[6] = f2bf(v1.z); t[7] = f2bf(v1.w);
    aw[kc] = t;
  }

  // h0 = 0
  {
    uint32_t* z = (uint32_t*)&ht[0][0][0];
    for (int i = tid; i < 2112; i += 512) z[i] = 0;
  }

  int* flg = flags + bg * 64;
  int ni = 0, ib = 0, fv = 0;
  // GATE: spin (rarely) on flags[ni]==2, acquire, DMA-issue chunk ni into
  // xs[ib], then PREFETCH flags[ni+1] so the steady-state gate is just an
  // acquire fence (~100 cyc) with the flag value already in-register.
#define GATE()                                                                \
  {                                                                           \
    while (fv < 2) {                                                          \
      if (lane == 0)                                                          \
        fv = __hip_atomic_load(flg + ni, __ATOMIC_RELAXED,                    \
                               __HIP_MEMORY_SCOPE_AGENT);                     \
      fv = __builtin_amdgcn_readfirstlane(fv);                                \
      if (fv < 2) __builtin_amdgcn_s_sleep(8);                                \
    }                                                                         \
    __builtin_amdgcn_fence(__ATOMIC_ACQUIRE, "agent");                        \
    const short* srcb =                                                       \
        xp16 + ((size_t)(ni * 8 + w) * 16 + bg) * 2048 + lane * 8;            \
    _Pragma("unroll") for (int j = 0; j < 4; ++j)                             \
        dma16(srcb + j * 512, &xs[ib][w][j * 512]);                           \
    ni++;                                                                     \
    ib = (ib == 2) ? 0 : ib + 1;                                              \
    fv = (ni < 64) ? 0 : 2;                                                   \
    if (ni < 64) {                                                            \
      if (lane == 0)                                                          \
        fv = __hip_atomic_load(flg + ni, __ATOMIC_RELAXED,                    \
                               __HIP_MEMORY_SCOPE_AGENT);                     \
      fv = __builtin_amdgcn_readfirstlane(fv);                                \
    }                                                                         \
  }

  GATE();  // issue chunk 0 -> xs[0]
  GATE();  // issue chunk 1 -> xs[1]
  // chunk 0 landed (4 outstanding = chunk 1); ht zeros drained (lgkm)
  asm volatile("s_waitcnt vmcnt(4) lgkmcnt(0)\n\ts_barrier" ::: "memory");

  const int gx = (w * 4 + q) * 64 + c * 4;  // xs offset: h-group w*4+q, batch c
  const int cb = (q & 1) * 64 + (2 * w + (q >> 1)) * 4;
  const short* bhp0 = &ht[0][c][4 * q];
  const short* bhp1 = &ht[1][c][4 * q];
  int rb3 = 0;  // read buffer = cc % 3

  for (int cc = 0; cc < 64; ++cc) {
    if (cc + 2 < 64) GATE()  // issue chunk cc+2 -> xs[(cc+2)%3]
    // preload the whole chunk's xp for this lane (h-independent)
    uint2 us[8];
#pragma unroll
    for (int s = 0; s < 8; ++s) us[s] = *(const uint2*)&xs[rb3][s][gx];
#pragma unroll
    for (int s = 0; s < 8; ++s) {
      const int rb = s & 1;  // global t = cc*8+s; cc even so parity = s&1
      const short* bp = rb ? bhp1 : bhp0;
      const short8 bh0 = ld_bh(bp + 0);
      const short8 bh1 = ld_bh(bp + 16);
      const short8 bh2 = ld_bh(bp + 32);
      const short8 bh3 = ld_bh(bp + 48);
      f32x4 a0 = {bflo(us[s].x), bfhi(us[s].x), bflo(us[s].y), bfhi(us[s].y)};
      f32x4 a2 = {0.f, 0.f, 0.f, 0.f};
      a0 = __builtin_amdgcn_mfma_f32_16x16x32_bf16(aw[0], bh0, a0, 0, 0, 0);
      a2 = __builtin_amdgcn_mfma_f32_16x16x32_bf16(aw[2], bh2, a2, 0, 0, 0);
      a0 = __builtin_amdgcn_mfma_f32_16x16x32_bf16(aw[1], bh1, a0, 0, 0, 0);
      a2 = __builtin_amdgcn_mfma_f32_16x16x32_bf16(aw[3], bh3, a2, 0, 0, 0);
      const f32x4 s0 = a0 + a2;
      uint2 w0;
      w0.x = pack2bf(tanhf_fast(s0[0]), tanhf_fast(s0[1]));
      w0.y = pack2bf(tanhf_fast(s0[2]), tanhf_fast(s0[3]));
      *(uint2*)&ht[rb ^ 1][c][cb] = w0;
      barrier_lds();
    }
    // chunk cc+1 must be landed; chunk cc+2 (4 DMAs) may stay in flight
    if (cc + 2 < 64)
      asm volatile("s_waitcnt vmcnt(4) lgkmcnt(0)\n\ts_barrier" ::: "memory");
    else
      asm volatile("s_waitcnt vmcnt(0) lgkmcnt(0)\n\ts_barrier" ::: "memory");
    rb3 = (rb3 == 2) ? 0 : rb3 + 1;
  }
#undef GATE

  // h_last in ht[0] (t=511 wrote rb^1 = 0). FC: 32 outputs/block.
  if (tid < 32) {
    const int bi = tid >> 1, cls = tid & 1;
    float s = fc_b[cls];
    const float* fw = fc_w + cls * HIDDEN;
#pragma unroll 4
    for (int g8 = 0; g8 < 16; ++g8) {
#pragma unroll
      for (int j = 0; j < 4; ++j) {
        s = fmaf(bf2f(ht[0][bi][g8 * 4 + j]), fw[g8 * 8 + j], s);
        s = fmaf(bf2f(ht[0][bi][64 + g8 * 4 + j]), fw[g8 * 8 + 4 + j], s);
      }
    }
    out[(bg * 16 + bi) * 2 + cls] = s;
  }
}

extern "C" void kernel_launch(void* const* d_in, const int* in_sizes, int n_in,
                              void* d_out, int out_size, void* d_ws, size_t ws_size,
                              hipStream_t stream) {
  const float* x    = (const float*)d_in[0];
  const float* W_ih = (const float*)d_in[1];
  const float* W_hh = (const float*)d_in[2];
  const float* b_ih = (const float*)d_in[3];
  const float* b_hh = (const float*)d_in[4];
  const float* fc_w = (const float*)d_in[5];
  const float* fc_b = (const float*)d_in[6];
  short* xp16 = (short*)d_ws;                        // 32 MiB bf16 [T][16bg][2048]
  int* flags  = (int*)((char*)d_ws + (33u << 20));   // 4 KB [16bg][64chunk]
  float* out  = (float*)d_out;

  hipMemsetAsync(flags, 0, 16 * 64 * sizeof(int), stream);
  rnn_fused<<<16 + 16 * (TSZ / 4), 512, 0, stream>>>(
      x, W_ih, W_hh, b_ih, b_hh, fc_w, fc_b, xp16, flags, out);
}